// Round 13
// baseline (513.549 us; speedup 1.0000x reference)
//
#include <hip/hip_runtime.h>
#include <hip/hip_bf16.h>
#include <cstdint>

typedef __bf16 bf16;
typedef __bf16 bf16x4 __attribute__((ext_vector_type(4)));
typedef __bf16 bf16x8 __attribute__((ext_vector_type(8)));
typedef float f32x4 __attribute__((ext_vector_type(4)));

#define GK 768   // inner K for both GEMMs
#define LN_EPS 1e-5f
#define NORM_EPS 1e-12f

// ---------------- async global->LDS helper ----------------
__device__ __forceinline__ void gl_lds16(const void* g, void* l) {
  __builtin_amdgcn_global_load_lds(
      (__attribute__((address_space(1))) uint32_t*)(uintptr_t)g,
      (__attribute__((address_space(3))) uint32_t*)(uintptr_t)l,
      16, 0, 0);
}

// ---------------- 0: merged tiled transpose + fp32->bf16 (both weights) -----
__global__ __launch_bounds__(256) void transpose_cvt2(const float* __restrict__ wq,
                                                      const float* __restrict__ wp,
                                                      bf16* __restrict__ wqt,
                                                      bf16* __restrict__ wpt) {
  __shared__ float tile[32][33];
  int bid = blockIdx.x;
  const float* w; bf16* wt; int Ncols, bx, by;
  if (bid < 1728) { w = wq; wt = wqt; Ncols = 2304; bx = bid % 72; by = bid / 72; }
  else { int b2 = bid - 1728; w = wp; wt = wpt; Ncols = 768; bx = b2 % 24; by = b2 / 24; }
  int tx = threadIdx.x & 31, ty = threadIdx.x >> 5;
  int c0 = bx * 32, r0 = by * 32;
  #pragma unroll
  for (int i = 0; i < 32; i += 8)
    tile[ty + i][tx] = w[(size_t)(r0 + ty + i) * Ncols + (c0 + tx)];
  __syncthreads();
  #pragma unroll
  for (int i = 0; i < 32; i += 8)
    wt[(size_t)(c0 + ty + i) * 768 + (r0 + tx)] = (bf16)tile[tx][ty + i];
}

// ---------------- 1: input LayerNorm -> bf16, wave-per-row ----------
__global__ __launch_bounds__(256) void ln_in_kernel(const float* __restrict__ x,
                                                    const float* __restrict__ g,
                                                    const float* __restrict__ b,
                                                    bf16* __restrict__ h) {
  int wave = threadIdx.x >> 6, lane = threadIdx.x & 63;
  int row = blockIdx.x * 4 + wave;
  const float* xr = x + (size_t)row * 768;
  float4 v0 = ((const float4*)xr)[lane];
  float4 v1 = ((const float4*)xr)[lane + 64];
  float4 v2 = ((const float4*)xr)[lane + 128];
  float s  = v0.x + v0.y + v0.z + v0.w + v1.x + v1.y + v1.z + v1.w
           + v2.x + v2.y + v2.z + v2.w;
  float ss = v0.x*v0.x + v0.y*v0.y + v0.z*v0.z + v0.w*v0.w
           + v1.x*v1.x + v1.y*v1.y + v1.z*v1.z + v1.w*v1.w
           + v2.x*v2.x + v2.y*v2.y + v2.z*v2.z + v2.w*v2.w;
  #pragma unroll
  for (int o = 32; o > 0; o >>= 1) {
    s  += __shfl_xor(s, o, 64);
    ss += __shfl_xor(ss, o, 64);
  }
  float mu  = s * (1.0f / 768.0f);
  float inv = rsqrtf(ss * (1.0f / 768.0f) - mu * mu + LN_EPS);
  bf16* hr = h + (size_t)row * 768;
  #pragma unroll
  for (int c = 0; c < 3; ++c) {
    float4 v = c == 0 ? v0 : (c == 1 ? v1 : v2);
    float4 gg = ((const float4*)g)[lane + c * 64];
    float4 bb = ((const float4*)b)[lane + c * 64];
    bf16x4 o;
    o[0] = (bf16)((v.x - mu) * inv * gg.x + bb.x);
    o[1] = (bf16)((v.y - mu) * inv * gg.y + bb.y);
    o[2] = (bf16)((v.z - mu) * inv * gg.z + bb.z);
    o[3] = (bf16)((v.w - mu) * inv * gg.w + bb.w);
    ((bf16x4*)hr)[lane + c * 64] = o;
  }
}

// ================= 128x128 bf16 GEMM, single-buffer LDS, 4 blocks/CU =======
// 256 threads = 4 waves (2m x 2n), wave = 64x64. BK=64 -> 12 K-tiles.
// LDS 32 KiB (single buf) -> 4 blocks/CU = 16 waves/CU: per-block full-drain
// stalls (VMC(0)) are hidden by 3 co-resident blocks (m114 overlap).
// LDS demand at full MFMA rate = 158 B/cyc vs ~112-128 capacity -> ceiling
// ~70-80% MfmaUtil; previous 2-block config was overlap-bound at 41%.
// T2 swizzle: XOR byte-bits 4-6 with row-bits 0-2 (involution, both sides).

#define SWZ(x) ((x) ^ ((((x) >> 7) & 7) << 4))

#define BAR __builtin_amdgcn_s_barrier()
#define VMC(n) asm volatile("s_waitcnt vmcnt(" #n ")" ::: "memory")
#define PRIO1 __builtin_amdgcn_s_setprio(1)
#define PRIO0 __builtin_amdgcn_s_setprio(0)

#define LDA1(i, ks) \
  af[i][ks] = *(const bf16x8*)(((const char*)As_) + SWZ((wm * 64 + (i) * 16 + llo) * 128 + (ks) * 64 + lhi * 16))
#define LDB1(j, ks) \
  bf[j][ks] = *(const bf16x8*)(((const char*)Bs_) + SWZ((wn * 64 + (j) * 16 + llo) * 128 + (ks) * 64 + lhi * 16))
#define RDALL do { \
  LDA1(0, 0); LDA1(1, 0); LDA1(2, 0); LDA1(3, 0); \
  LDB1(0, 0); LDB1(1, 0); LDB1(2, 0); LDB1(3, 0); \
  LDA1(0, 1); LDA1(1, 1); LDA1(2, 1); LDA1(3, 1); \
  LDB1(0, 1); LDB1(1, 1); LDB1(2, 1); LDB1(3, 1); } while (0)

#define MF1(m, n, ks) \
  acc[m][n] = __builtin_amdgcn_mfma_f32_16x16x32_bf16(af[m][ks], bf[n][ks], acc[m][n], 0, 0, 0)
#define MFALL do { PRIO1; \
  MF1(0,0,0); MF1(0,1,0); MF1(0,2,0); MF1(0,3,0); \
  MF1(1,0,0); MF1(1,1,0); MF1(1,2,0); MF1(1,3,0); \
  MF1(2,0,0); MF1(2,1,0); MF1(2,2,0); MF1(2,3,0); \
  MF1(3,0,0); MF1(3,1,0); MF1(3,2,0); MF1(3,3,0); \
  MF1(0,0,1); MF1(0,1,1); MF1(0,2,1); MF1(0,3,1); \
  MF1(1,0,1); MF1(1,1,1); MF1(1,2,1); MF1(1,3,1); \
  MF1(2,0,1); MF1(2,1,1); MF1(2,2,1); MF1(2,3,1); \
  MF1(3,0,1); MF1(3,1,1); MF1(3,2,1); MF1(3,3,1); \
  PRIO0; } while (0)

#define STAGE(t) do { \
  gl_lds16(A  + srcA[0] + (t) * 64, &As_[0 * 2048 + wave * 512]); \
  gl_lds16(A  + srcA[1] + (t) * 64, &As_[1 * 2048 + wave * 512]); \
  gl_lds16(A  + srcA[2] + (t) * 64, &As_[2 * 2048 + wave * 512]); \
  gl_lds16(A  + srcA[3] + (t) * 64, &As_[3 * 2048 + wave * 512]); \
  gl_lds16(Bt + srcB[0] + (t) * 64, &Bs_[0 * 2048 + wave * 512]); \
  gl_lds16(Bt + srcB[1] + (t) * 64, &Bs_[1 * 2048 + wave * 512]); \
  gl_lds16(Bt + srcB[2] + (t) * 64, &Bs_[2 * 2048 + wave * 512]); \
  gl_lds16(Bt + srcB[3] + (t) * 64, &Bs_[3 * 2048 + wave * 512]); } while (0)

template <bool OUT_BF16>
__global__ __launch_bounds__(256, 4) void gemm128(const bf16* __restrict__ A,
                                                  const bf16* __restrict__ Bt,
                                                  void* __restrict__ Cv,
                                                  int Nn, int NBN) {
  __shared__ __align__(16) bf16 As_[8192];   // 16KB, single buffer
  __shared__ __align__(16) bf16 Bs_[8192];
  const int tid = threadIdx.x;
  const int wave = tid >> 6, lane = tid & 63;
  const int llo = lane & 15, lhi = lane >> 4;
  const int wm = wave >> 1, wn = wave & 1;

  const int nwg = gridDim.x, bid = blockIdx.x;
  const int wg = (bid & 7) * (nwg >> 3) + (bid >> 3);
  const int rb = wg / NBN, cb = wg - rb * NBN;
  const int brow = rb * 128, bcol = cb * 128;

  uint32_t srcA[4], srcB[4];
  #pragma unroll
  for (int q = 0; q < 4; ++q) {
    int d = q * 4096 + tid * 16;
    int a = SWZ(d);
    int r = a >> 7, c = (a & 127) >> 1;
    srcA[q] = (uint32_t)(brow + r) * GK + c;
    srcB[q] = (uint32_t)(bcol + r) * GK + c;
  }

  f32x4 acc[4][4];
  #pragma unroll
  for (int m = 0; m < 4; ++m)
    #pragma unroll
    for (int n = 0; n < 4; ++n) acc[m][n] = (f32x4){0.f, 0.f, 0.f, 0.f};

  bf16x8 af[4][2], bf[4][2];

  STAGE(0);
  VMC(0);
  BAR;

  #pragma unroll
  for (int t = 0; t < 12; ++t) {
    RDALL;
    MFALL;
    if (t < 11) {
      BAR;             // all waves done reading tile t
      STAGE(t + 1);    // overwrite single buffer
      VMC(0);          // stage complete (per-block stall, CU-level hidden)
      BAR;
    }
  }

  #pragma unroll
  for (int m = 0; m < 4; ++m) {
    #pragma unroll
    for (int n = 0; n < 4; ++n) {
      int row = brow + wm * 64 + m * 16 + lhi * 4;
      int col = bcol + wn * 64 + n * 16 + llo;
      #pragma unroll
      for (int r2 = 0; r2 < 4; ++r2) {
        if (OUT_BF16)
          ((bf16*)Cv)[(size_t)(row + r2) * Nn + col] = (bf16)acc[m][n][r2];
        else
          ((float*)Cv)[(size_t)(row + r2) * Nn + col] = acc[m][n][r2];
      }
    }
  }
}

// ---------------- 3a: kv partial sums, k-norm inline, 4 blocks/CU ----------
__global__ __launch_bounds__(256) void kv_partial(const bf16* __restrict__ qkv,
                                                  float* __restrict__ kvp) {
  __shared__ float sm[4][768];
  int b = blockIdx.x >> 7, chunk = blockIdx.x & 127;
  int wave = threadIdx.x >> 6, lane = threadIdx.x & 63;
  const bf16* base = qkv + ((size_t)(b * 4096 + chunk * 32 + wave * 8)) * 2304;
  float acc8[8] = {}, acc4[4] = {};
  #pragma unroll
  for (int i = 0; i < 8; ++i) {
    const bf16* kr = base + (size_t)i * 2304 + 768;
    const bf16* vr = kr + 768;
    bf16x8 k8 = *(const bf16x8*)(kr + lane * 8);
    bf16x4 k4 = *(const bf16x4*)(kr + 512 + lane * 4);
    bf16x8 v8 = *(const bf16x8*)(vr + lane * 8);
    bf16x4 v4 = *(const bf16x4*)(vr + 512 + lane * 4);
    float kf8[8], kf4[4];
    float ssk = 0.f;
    #pragma unroll
    for (int j = 0; j < 8; ++j) { kf8[j] = (float)k8[j]; ssk += kf8[j] * kf8[j]; }
    #pragma unroll
    for (int j = 0; j < 4; ++j) { kf4[j] = (float)k4[j]; ssk += kf4[j] * kf4[j]; }
    #pragma unroll
    for (int off = 32; off > 0; off >>= 1) ssk += __shfl_xor(ssk, off, 64);
    float wi = 1.0f / fmaxf(sqrtf(ssk), NORM_EPS);
    #pragma unroll
    for (int j = 0; j < 8; ++j) acc8[j] += kf8[j] * (float)v8[j] * wi;
    #pragma unroll
    for (int j = 0; j < 4; ++j) acc4[j] += kf4[j] * (float)v4[j] * wi;
  }
  #pragma unroll
  for (int j = 0; j < 8; ++j) sm[wave][lane * 8 + j] = acc8[j];
  #pragma unroll
  for (int j = 0; j < 4; ++j) sm[wave][512 + lane * 4 + j] = acc4[j];
  __syncthreads();
  int t = threadIdx.x;
  #pragma unroll
  for (int c = 0; c < 3; ++c) {
    int e = c * 256 + t;
    kvp[(size_t)blockIdx.x * 768 + e] = sm[0][e] + sm[1][e] + sm[2][e] + sm[3][e];
  }
}

// ---------------- 3b: reduce 128 partials -> kv[8][768] ----------------
__global__ __launch_bounds__(256) void kv_reduce(const float* __restrict__ kvp,
                                                 float* __restrict__ kv) {
  int i = blockIdx.x * 256 + threadIdx.x;
  int b = i / 768, e = i - b * 768;
  float s = 0.f;
  #pragma unroll 8
  for (int c = 0; c < 128; ++c) s += kvp[(size_t)(b * 128 + c) * 768 + e];
  kv[i] = s;
}

// ---------------- 4: attn+LN, wave-per-row (q-norm inline) ----------------
__global__ __launch_bounds__(256) void attn_ln_kernel(const bf16* __restrict__ qkv,
                                                      const float* __restrict__ kv,
                                                      const float* __restrict__ g,
                                                      const float* __restrict__ b,
                                                      bf16* __restrict__ a) {
  int wave = threadIdx.x >> 6, lane = threadIdx.x & 63;
  int row = blockIdx.x * 4 + wave;
  int bt = row >> 12;
  const bf16* qr = qkv + (size_t)row * 2304;
  bf16x4 q4[3];
  float qf[12];
  float sq = 0.f;
  #pragma unroll
  for (int c = 0; c < 3; ++c) {
    q4[c] = ((const bf16x4*)qr)[lane + c * 64];
    #pragma unroll
    for (int j = 0; j < 4; ++j) {
      float f = (float)q4[c][j];
      qf[c * 4 + j] = f;
      sq += f * f;
    }
  }
  #pragma unroll
  for (int o = 32; o > 0; o >>= 1) sq += __shfl_xor(sq, o, 64);
  float iq = 1.0f / fmaxf(sqrtf(sq), NORM_EPS);
  const float4* kvr = (const float4*)(kv + bt * 768);
  float av[12];
  float s = 0.f, ss = 0.f;
  #pragma unroll
  for (int c = 0; c < 3; ++c) {
    float4 kv4 = kvr[lane + c * 64];
    av[c * 4 + 0] = qf[c * 4 + 0] * iq * kv4.x;
    av[c * 4 + 1] = qf[c * 4 + 1] * iq * kv4.y;
    av[c * 4 + 2] = qf[c * 4 + 2] * iq * kv4.z;
    av[c * 4 + 3] = qf[c * 4 + 3] * iq * kv4.w;
    #pragma unroll
    for (int j = 0; j < 4; ++j) { s += av[c * 4 + j]; ss += av[c * 4 + j] * av[c * 4 + j]; }
  }
  #pragma unroll
  for (int o = 32; o > 0; o >>= 1) {
    s  += __shfl_xor(s, o, 64);
    ss += __shfl_xor(ss, o, 64);
  }
  float mu  = s * (1.0f / 768.0f);
  float inv = rsqrtf(ss * (1.0f / 768.0f) - mu * mu + LN_EPS);
  bf16* ar = a + (size_t)row * 768;
  #pragma unroll
  for (int c = 0; c < 3; ++c) {
    float4 gg = ((const float4*)g)[lane + c * 64];
    float4 bb = ((const float4*)b)[lane + c * 64];
    bf16x4 o;
    o[0] = (bf16)((av[c * 4 + 0] - mu) * inv * gg.x + bb.x);
    o[1] = (bf16)((av[c * 4 + 1] - mu) * inv * gg.y + bb.y);
    o[2] = (bf16)((av[c * 4 + 2] - mu) * inv * gg.z + bb.z);
    o[3] = (bf16)((av[c * 4 + 3] - mu) * inv * gg.w + bb.w);
    ((bf16x4*)ar)[lane + c * 64] = o;
  }
}

// ---------------- launcher ----------------
extern "C" void kernel_launch(void* const* d_in, const int* in_sizes, int n_in,
                              void* d_out, int out_size, void* d_ws, size_t ws_size,
                              hipStream_t stream) {
  const float* x      = (const float*)d_in[0];
  const float* w_qkv  = (const float*)d_in[1];
  const float* w_proj = (const float*)d_in[2];
  const float* g_in   = (const float*)d_in[3];
  const float* b_in   = (const float*)d_in[4];
  const float* g_out  = (const float*)d_in[5];
  const float* b_out  = (const float*)d_in[6];

  char* ws = (char*)d_ws;
  bf16*  wqkvt  = (bf16*)(ws);                              // [2304][768] bf16
  bf16*  wprojt = (bf16*)(ws + 3538944);                    // [768][768]  bf16
  bf16*  h      = (bf16*)(ws + 4718592);                    // [32768][768] bf16 (reused as 'a')
  bf16*  qkv    = (bf16*)(ws + 55050240);                   // [32768][2304] bf16
  float* kvp    = (float*)(ws + 206045184);                 // [1024][768] fp32
  float* kv     = (float*)(ws + 209190912);                 // [8][768]

  transpose_cvt2<<<2304, 256, 0, stream>>>(w_qkv, w_proj, wqkvt, wprojt);
  ln_in_kernel<<<8192, 256, 0, stream>>>(x, g_in, b_in, h);
  gemm128<true><<<256 * 18, 256, 0, stream>>>(h, wqkvt, (void*)qkv, 2304, 18);
  kv_partial<<<1024, 256, 0, stream>>>(qkv, kvp);
  kv_reduce<<<24, 256, 0, stream>>>(kvp, kv);
  attn_ln_kernel<<<8192, 256, 0, stream>>>(qkv, kv, g_out, b_out, h);
  gemm128<false><<<256 * 6, 256, 0, stream>>>(h, wprojt, d_out, 768, 6);
}

// Round 14
// 252.281 us; speedup vs baseline: 2.0356x; 2.0356x over previous
//
#include <hip/hip_runtime.h>
#include <hip/hip_bf16.h>
#include <cstdint>

typedef __bf16 bf16;
typedef __bf16 bf16x4 __attribute__((ext_vector_type(4)));
typedef __bf16 bf16x8 __attribute__((ext_vector_type(8)));
typedef float f32x4 __attribute__((ext_vector_type(4)));

#define GK 768   // inner K for both GEMMs
#define LN_EPS 1e-5f
#define NORM_EPS 1e-12f

// ---------------- async global->LDS helper ----------------
__device__ __forceinline__ void gl_lds16(const void* g, void* l) {
  __builtin_amdgcn_global_load_lds(
      (__attribute__((address_space(1))) uint32_t*)(uintptr_t)g,
      (__attribute__((address_space(3))) uint32_t*)(uintptr_t)l,
      16, 0, 0);
}

// ---------------- 0: merged tiled transpose + fp32->bf16 (both weights) -----
__global__ __launch_bounds__(256) void transpose_cvt2(const float* __restrict__ wq,
                                                      const float* __restrict__ wp,
                                                      bf16* __restrict__ wqt,
                                                      bf16* __restrict__ wpt) {
  __shared__ float tile[32][33];
  int bid = blockIdx.x;
  const float* w; bf16* wt; int Ncols, bx, by;
  if (bid < 1728) { w = wq; wt = wqt; Ncols = 2304; bx = bid % 72; by = bid / 72; }
  else { int b2 = bid - 1728; w = wp; wt = wpt; Ncols = 768; bx = b2 % 24; by = b2 / 24; }
  int tx = threadIdx.x & 31, ty = threadIdx.x >> 5;
  int c0 = bx * 32, r0 = by * 32;
  #pragma unroll
  for (int i = 0; i < 32; i += 8)
    tile[ty + i][tx] = w[(size_t)(r0 + ty + i) * Ncols + (c0 + tx)];
  __syncthreads();
  #pragma unroll
  for (int i = 0; i < 32; i += 8)
    wt[(size_t)(c0 + ty + i) * 768 + (r0 + tx)] = (bf16)tile[tx][ty + i];
}

// ---------------- 1: input LayerNorm -> bf16, wave-per-row ----------
__global__ __launch_bounds__(256) void ln_in_kernel(const float* __restrict__ x,
                                                    const float* __restrict__ g,
                                                    const float* __restrict__ b,
                                                    bf16* __restrict__ h) {
  int wave = threadIdx.x >> 6, lane = threadIdx.x & 63;
  int row = blockIdx.x * 4 + wave;
  const float* xr = x + (size_t)row * 768;
  float4 v0 = ((const float4*)xr)[lane];
  float4 v1 = ((const float4*)xr)[lane + 64];
  float4 v2 = ((const float4*)xr)[lane + 128];
  float s  = v0.x + v0.y + v0.z + v0.w + v1.x + v1.y + v1.z + v1.w
           + v2.x + v2.y + v2.z + v2.w;
  float ss = v0.x*v0.x + v0.y*v0.y + v0.z*v0.z + v0.w*v0.w
           + v1.x*v1.x + v1.y*v1.y + v1.z*v1.z + v1.w*v1.w
           + v2.x*v2.x + v2.y*v2.y + v2.z*v2.z + v2.w*v2.w;
  #pragma unroll
  for (int o = 32; o > 0; o >>= 1) {
    s  += __shfl_xor(s, o, 64);
    ss += __shfl_xor(ss, o, 64);
  }
  float mu  = s * (1.0f / 768.0f);
  float inv = rsqrtf(ss * (1.0f / 768.0f) - mu * mu + LN_EPS);
  bf16* hr = h + (size_t)row * 768;
  #pragma unroll
  for (int c = 0; c < 3; ++c) {
    float4 v = c == 0 ? v0 : (c == 1 ? v1 : v2);
    float4 gg = ((const float4*)g)[lane + c * 64];
    float4 bb = ((const float4*)b)[lane + c * 64];
    bf16x4 o;
    o[0] = (bf16)((v.x - mu) * inv * gg.x + bb.x);
    o[1] = (bf16)((v.y - mu) * inv * gg.y + bb.y);
    o[2] = (bf16)((v.z - mu) * inv * gg.z + bb.z);
    o[3] = (bf16)((v.w - mu) * inv * gg.w + bb.w);
    ((bf16x4*)hr)[lane + c * 64] = o;
  }
}

// ================= 128x128 bf16 GEMM, single-buffer LDS =====================
// 256 threads = 4 waves (2m x 2n), wave = 64x64. BK=64 -> 12 K-tiles.
// LDS 32 KiB single buffer; __launch_bounds__(256,2) so the allocator keeps
// the round-8 register footprint (~88 VGPR). Occupancy then lands at
// 4 blocks/CU naturally (VGPR 88 -> 4 waves/EU; LDS 32KB -> 5 blocks).
// Per-block VMC(0) drains are hidden by 3 co-resident blocks (m114).
// T2 swizzle: XOR byte-bits 4-6 with row-bits 0-2 (involution, both sides).

#define SWZ(x) ((x) ^ ((((x) >> 7) & 7) << 4))

#define BAR __builtin_amdgcn_s_barrier()
#define VMC(n) asm volatile("s_waitcnt vmcnt(" #n ")" ::: "memory")
#define PRIO1 __builtin_amdgcn_s_setprio(1)
#define PRIO0 __builtin_amdgcn_s_setprio(0)

#define LDA1(i, ks) \
  af[i][ks] = *(const bf16x8*)(((const char*)As_) + SWZ((wm * 64 + (i) * 16 + llo) * 128 + (ks) * 64 + lhi * 16))
#define LDB1(j, ks) \
  bf[j][ks] = *(const bf16x8*)(((const char*)Bs_) + SWZ((wn * 64 + (j) * 16 + llo) * 128 + (ks) * 64 + lhi * 16))
#define RDALL do { \
  LDA1(0, 0); LDA1(1, 0); LDA1(2, 0); LDA1(3, 0); \
  LDB1(0, 0); LDB1(1, 0); LDB1(2, 0); LDB1(3, 0); \
  LDA1(0, 1); LDA1(1, 1); LDA1(2, 1); LDA1(3, 1); \
  LDB1(0, 1); LDB1(1, 1); LDB1(2, 1); LDB1(3, 1); } while (0)

#define MF1(m, n, ks) \
  acc[m][n] = __builtin_amdgcn_mfma_f32_16x16x32_bf16(af[m][ks], bf[n][ks], acc[m][n], 0, 0, 0)
#define MFALL do { PRIO1; \
  MF1(0,0,0); MF1(0,1,0); MF1(0,2,0); MF1(0,3,0); \
  MF1(1,0,0); MF1(1,1,0); MF1(1,2,0); MF1(1,3,0); \
  MF1(2,0,0); MF1(2,1,0); MF1(2,2,0); MF1(2,3,0); \
  MF1(3,0,0); MF1(3,1,0); MF1(3,2,0); MF1(3,3,0); \
  MF1(0,0,1); MF1(0,1,1); MF1(0,2,1); MF1(0,3,1); \
  MF1(1,0,1); MF1(1,1,1); MF1(1,2,1); MF1(1,3,1); \
  MF1(2,0,1); MF1(2,1,1); MF1(2,2,1); MF1(2,3,1); \
  MF1(3,0,1); MF1(3,1,1); MF1(3,2,1); MF1(3,3,1); \
  PRIO0; } while (0)

#define STAGE(t) do { \
  gl_lds16(A  + srcA[0] + (t) * 64, &As_[0 * 2048 + wave * 512]); \
  gl_lds16(A  + srcA[1] + (t) * 64, &As_[1 * 2048 + wave * 512]); \
  gl_lds16(A  + srcA[2] + (t) * 64, &As_[2 * 2048 + wave * 512]); \
  gl_lds16(A  + srcA[3] + (t) * 64, &As_[3 * 2048 + wave * 512]); \
  gl_lds16(Bt + srcB[0] + (t) * 64, &Bs_[0 * 2048 + wave * 512]); \
  gl_lds16(Bt + srcB[1] + (t) * 64, &Bs_[1 * 2048 + wave * 512]); \
  gl_lds16(Bt + srcB[2] + (t) * 64, &Bs_[2 * 2048 + wave * 512]); \
  gl_lds16(Bt + srcB[3] + (t) * 64, &Bs_[3 * 2048 + wave * 512]); } while (0)

template <bool OUT_BF16>
__global__ __launch_bounds__(256, 2) void gemm128(const bf16* __restrict__ A,
                                                  const bf16* __restrict__ Bt,
                                                  void* __restrict__ Cv,
                                                  int Nn, int NBN) {
  __shared__ __align__(16) bf16 As_[8192];   // 16KB, single buffer
  __shared__ __align__(16) bf16 Bs_[8192];
  const int tid = threadIdx.x;
  const int wave = tid >> 6, lane = tid & 63;
  const int llo = lane & 15, lhi = lane >> 4;
  const int wm = wave >> 1, wn = wave & 1;

  const int nwg = gridDim.x, bid = blockIdx.x;
  const int wg = (bid & 7) * (nwg >> 3) + (bid >> 3);
  const int rb = wg / NBN, cb = wg - rb * NBN;
  const int brow = rb * 128, bcol = cb * 128;

  uint32_t srcA[4], srcB[4];
  #pragma unroll
  for (int q = 0; q < 4; ++q) {
    int d = q * 4096 + tid * 16;
    int a = SWZ(d);
    int r = a >> 7, c = (a & 127) >> 1;
    srcA[q] = (uint32_t)(brow + r) * GK + c;
    srcB[q] = (uint32_t)(bcol + r) * GK + c;
  }

  f32x4 acc[4][4];
  #pragma unroll
  for (int m = 0; m < 4; ++m)
    #pragma unroll
    for (int n = 0; n < 4; ++n) acc[m][n] = (f32x4){0.f, 0.f, 0.f, 0.f};

  bf16x8 af[4][2], bf[4][2];

  STAGE(0);
  VMC(0);
  BAR;

  #pragma unroll
  for (int t = 0; t < 12; ++t) {
    RDALL;
    MFALL;
    if (t < 11) {
      BAR;             // all waves done reading tile t
      STAGE(t + 1);    // overwrite single buffer
      VMC(0);          // stage complete (per-block stall, CU-level hidden)
      BAR;
    }
  }

  #pragma unroll
  for (int m = 0; m < 4; ++m) {
    #pragma unroll
    for (int n = 0; n < 4; ++n) {
      int row = brow + wm * 64 + m * 16 + lhi * 4;
      int col = bcol + wn * 64 + n * 16 + llo;
      #pragma unroll
      for (int r2 = 0; r2 < 4; ++r2) {
        if (OUT_BF16)
          ((bf16*)Cv)[(size_t)(row + r2) * Nn + col] = (bf16)acc[m][n][r2];
        else
          ((float*)Cv)[(size_t)(row + r2) * Nn + col] = acc[m][n][r2];
      }
    }
  }
}

// ---------------- 3a: kv partial sums, k-norm inline, 4 blocks/CU ----------
__global__ __launch_bounds__(256) void kv_partial(const bf16* __restrict__ qkv,
                                                  float* __restrict__ kvp) {
  __shared__ float sm[4][768];
  int b = blockIdx.x >> 7, chunk = blockIdx.x & 127;
  int wave = threadIdx.x >> 6, lane = threadIdx.x & 63;
  const bf16* base = qkv + ((size_t)(b * 4096 + chunk * 32 + wave * 8)) * 2304;
  float acc8[8] = {}, acc4[4] = {};
  #pragma unroll
  for (int i = 0; i < 8; ++i) {
    const bf16* kr = base + (size_t)i * 2304 + 768;
    const bf16* vr = kr + 768;
    bf16x8 k8 = *(const bf16x8*)(kr + lane * 8);
    bf16x4 k4 = *(const bf16x4*)(kr + 512 + lane * 4);
    bf16x8 v8 = *(const bf16x8*)(vr + lane * 8);
    bf16x4 v4 = *(const bf16x4*)(vr + 512 + lane * 4);
    float kf8[8], kf4[4];
    float ssk = 0.f;
    #pragma unroll
    for (int j = 0; j < 8; ++j) { kf8[j] = (float)k8[j]; ssk += kf8[j] * kf8[j]; }
    #pragma unroll
    for (int j = 0; j < 4; ++j) { kf4[j] = (float)k4[j]; ssk += kf4[j] * kf4[j]; }
    #pragma unroll
    for (int off = 32; off > 0; off >>= 1) ssk += __shfl_xor(ssk, off, 64);
    float wi = 1.0f / fmaxf(sqrtf(ssk), NORM_EPS);
    #pragma unroll
    for (int j = 0; j < 8; ++j) acc8[j] += kf8[j] * (float)v8[j] * wi;
    #pragma unroll
    for (int j = 0; j < 4; ++j) acc4[j] += kf4[j] * (float)v4[j] * wi;
  }
  #pragma unroll
  for (int j = 0; j < 8; ++j) sm[wave][lane * 8 + j] = acc8[j];
  #pragma unroll
  for (int j = 0; j < 4; ++j) sm[wave][512 + lane * 4 + j] = acc4[j];
  __syncthreads();
  int t = threadIdx.x;
  #pragma unroll
  for (int c = 0; c < 3; ++c) {
    int e = c * 256 + t;
    kvp[(size_t)blockIdx.x * 768 + e] = sm[0][e] + sm[1][e] + sm[2][e] + sm[3][e];
  }
}

// ---------------- 3b: reduce 128 partials -> kv[8][768] ----------------
__global__ __launch_bounds__(256) void kv_reduce(const float* __restrict__ kvp,
                                                 float* __restrict__ kv) {
  int i = blockIdx.x * 256 + threadIdx.x;
  int b = i / 768, e = i - b * 768;
  float s = 0.f;
  #pragma unroll 8
  for (int c = 0; c < 128; ++c) s += kvp[(size_t)(b * 128 + c) * 768 + e];
  kv[i] = s;
}

// ---------------- 4: attn+LN, wave-per-row (q-norm inline) ----------------
__global__ __launch_bounds__(256) void attn_ln_kernel(const bf16* __restrict__ qkv,
                                                      const float* __restrict__ kv,
                                                      const float* __restrict__ g,
                                                      const float* __restrict__ b,
                                                      bf16* __restrict__ a) {
  int wave = threadIdx.x >> 6, lane = threadIdx.x & 63;
  int row = blockIdx.x * 4 + wave;
  int bt = row >> 12;
  const bf16* qr = qkv + (size_t)row * 2304;
  bf16x4 q4[3];
  float qf[12];
  float sq = 0.f;
  #pragma unroll
  for (int c = 0; c < 3; ++c) {
    q4[c] = ((const bf16x4*)qr)[lane + c * 64];
    #pragma unroll
    for (int j = 0; j < 4; ++j) {
      float f = (float)q4[c][j];
      qf[c * 4 + j] = f;
      sq += f * f;
    }
  }
  #pragma unroll
  for (int o = 32; o > 0; o >>= 1) sq += __shfl_xor(sq, o, 64);
  float iq = 1.0f / fmaxf(sqrtf(sq), NORM_EPS);
  const float4* kvr = (const float4*)(kv + bt * 768);
  float av[12];
  float s = 0.f, ss = 0.f;
  #pragma unroll
  for (int c = 0; c < 3; ++c) {
    float4 kv4 = kvr[lane + c * 64];
    av[c * 4 + 0] = qf[c * 4 + 0] * iq * kv4.x;
    av[c * 4 + 1] = qf[c * 4 + 1] * iq * kv4.y;
    av[c * 4 + 2] = qf[c * 4 + 2] * iq * kv4.z;
    av[c * 4 + 3] = qf[c * 4 + 3] * iq * kv4.w;
    #pragma unroll
    for (int j = 0; j < 4; ++j) { s += av[c * 4 + j]; ss += av[c * 4 + j] * av[c * 4 + j]; }
  }
  #pragma unroll
  for (int o = 32; o > 0; o >>= 1) {
    s  += __shfl_xor(s, o, 64);
    ss += __shfl_xor(ss, o, 64);
  }
  float mu  = s * (1.0f / 768.0f);
  float inv = rsqrtf(ss * (1.0f / 768.0f) - mu * mu + LN_EPS);
  bf16* ar = a + (size_t)row * 768;
  #pragma unroll
  for (int c = 0; c < 3; ++c) {
    float4 gg = ((const float4*)g)[lane + c * 64];
    float4 bb = ((const float4*)b)[lane + c * 64];
    bf16x4 o;
    o[0] = (bf16)((av[c * 4 + 0] - mu) * inv * gg.x + bb.x);
    o[1] = (bf16)((av[c * 4 + 1] - mu) * inv * gg.y + bb.y);
    o[2] = (bf16)((av[c * 4 + 2] - mu) * inv * gg.z + bb.z);
    o[3] = (bf16)((av[c * 4 + 3] - mu) * inv * gg.w + bb.w);
    ((bf16x4*)ar)[lane + c * 64] = o;
  }
}

// ---------------- launcher ----------------
extern "C" void kernel_launch(void* const* d_in, const int* in_sizes, int n_in,
                              void* d_out, int out_size, void* d_ws, size_t ws_size,
                              hipStream_t stream) {
  const float* x      = (const float*)d_in[0];
  const float* w_qkv  = (const float*)d_in[1];
  const float* w_proj = (const float*)d_in[2];
  const float* g_in   = (const float*)d_in[3];
  const float* b_in   = (const float*)d_in[4];
  const float* g_out  = (const float*)d_in[5];
  const float* b_out  = (const float*)d_in[6];

  char* ws = (char*)d_ws;
  bf16*  wqkvt  = (bf16*)(ws);                              // [2304][768] bf16
  bf16*  wprojt = (bf16*)(ws + 3538944);                    // [768][768]  bf16
  bf16*  h      = (bf16*)(ws + 4718592);                    // [32768][768] bf16 (reused as 'a')
  bf16*  qkv    = (bf16*)(ws + 55050240);                   // [32768][2304] bf16
  float* kvp    = (float*)(ws + 206045184);                 // [1024][768] fp32
  float* kv     = (float*)(ws + 209190912);                 // [8][768]

  transpose_cvt2<<<2304, 256, 0, stream>>>(w_qkv, w_proj, wqkvt, wprojt);
  ln_in_kernel<<<8192, 256, 0, stream>>>(x, g_in, b_in, h);
  gemm128<true><<<256 * 18, 256, 0, stream>>>(h, wqkvt, (void*)qkv, 2304, 18);
  kv_partial<<<1024, 256, 0, stream>>>(qkv, kvp);
  kv_reduce<<<24, 256, 0, stream>>>(kvp, kv);
  attn_ln_kernel<<<8192, 256, 0, stream>>>(qkv, kv, g_out, b_out, h);
  gemm128<false><<<256 * 6, 256, 0, stream>>>(h, wprojt, d_out, 768, 6);
}

// Round 15
// 246.644 us; speedup vs baseline: 2.0821x; 1.0229x over previous
//
#include <hip/hip_runtime.h>
#include <hip/hip_bf16.h>
#include <cstdint>

typedef __bf16 bf16;
typedef __bf16 bf16x4 __attribute__((ext_vector_type(4)));
typedef __bf16 bf16x8 __attribute__((ext_vector_type(8)));
typedef float f32x4 __attribute__((ext_vector_type(4)));

#define GK 768   // inner K for both GEMMs
#define LN_EPS 1e-5f
#define NORM_EPS 1e-12f

// ---------------- async global->LDS helper ----------------
__device__ __forceinline__ void gl_lds16(const void* g, void* l) {
  __builtin_amdgcn_global_load_lds(
      (__attribute__((address_space(1))) uint32_t*)(uintptr_t)g,
      (__attribute__((address_space(3))) uint32_t*)(uintptr_t)l,
      16, 0, 0);
}

// ---------------- 0: merged tiled transpose + fp32->bf16 (both weights) -----
__global__ __launch_bounds__(256) void transpose_cvt2(const float* __restrict__ wq,
                                                      const float* __restrict__ wp,
                                                      bf16* __restrict__ wqt,
                                                      bf16* __restrict__ wpt) {
  __shared__ float tile[32][33];
  int bid = blockIdx.x;
  const float* w; bf16* wt; int Ncols, bx, by;
  if (bid < 1728) { w = wq; wt = wqt; Ncols = 2304; bx = bid % 72; by = bid / 72; }
  else { int b2 = bid - 1728; w = wp; wt = wpt; Ncols = 768; bx = b2 % 24; by = b2 / 24; }
  int tx = threadIdx.x & 31, ty = threadIdx.x >> 5;
  int c0 = bx * 32, r0 = by * 32;
  #pragma unroll
  for (int i = 0; i < 32; i += 8)
    tile[ty + i][tx] = w[(size_t)(r0 + ty + i) * Ncols + (c0 + tx)];
  __syncthreads();
  #pragma unroll
  for (int i = 0; i < 32; i += 8)
    wt[(size_t)(c0 + ty + i) * 768 + (r0 + tx)] = (bf16)tile[tx][ty + i];
}

// ---------------- 1: input LayerNorm -> bf16, wave-per-row ----------
__global__ __launch_bounds__(256) void ln_in_kernel(const float* __restrict__ x,
                                                    const float* __restrict__ g,
                                                    const float* __restrict__ b,
                                                    bf16* __restrict__ h) {
  int wave = threadIdx.x >> 6, lane = threadIdx.x & 63;
  int row = blockIdx.x * 4 + wave;
  const float* xr = x + (size_t)row * 768;
  float4 v0 = ((const float4*)xr)[lane];
  float4 v1 = ((const float4*)xr)[lane + 64];
  float4 v2 = ((const float4*)xr)[lane + 128];
  float s  = v0.x + v0.y + v0.z + v0.w + v1.x + v1.y + v1.z + v1.w
           + v2.x + v2.y + v2.z + v2.w;
  float ss = v0.x*v0.x + v0.y*v0.y + v0.z*v0.z + v0.w*v0.w
           + v1.x*v1.x + v1.y*v1.y + v1.z*v1.z + v1.w*v1.w
           + v2.x*v2.x + v2.y*v2.y + v2.z*v2.z + v2.w*v2.w;
  #pragma unroll
  for (int o = 32; o > 0; o >>= 1) {
    s  += __shfl_xor(s, o, 64);
    ss += __shfl_xor(ss, o, 64);
  }
  float mu  = s * (1.0f / 768.0f);
  float inv = rsqrtf(ss * (1.0f / 768.0f) - mu * mu + LN_EPS);
  bf16* hr = h + (size_t)row * 768;
  #pragma unroll
  for (int c = 0; c < 3; ++c) {
    float4 v = c == 0 ? v0 : (c == 1 ? v1 : v2);
    float4 gg = ((const float4*)g)[lane + c * 64];
    float4 bb = ((const float4*)b)[lane + c * 64];
    bf16x4 o;
    o[0] = (bf16)((v.x - mu) * inv * gg.x + bb.x);
    o[1] = (bf16)((v.y - mu) * inv * gg.y + bb.y);
    o[2] = (bf16)((v.z - mu) * inv * gg.z + bb.z);
    o[3] = (bf16)((v.w - mu) * inv * gg.w + bb.w);
    ((bf16x4*)hr)[lane + c * 64] = o;
  }
}

// ======== shared GEMM pieces: 128x128, 4 waves (2m x 2n), wave 64x64 =======
// T2 swizzle: XOR byte-bits 4-6 with row-bits 0-2 (involution, both sides).
// Both variants measured at the 128^2-structure ceiling (~920-930 TF):
//   gemm128s (single-buf, 4 blocks/CU) best for GEMM1 (123.6 us, r14)
//   gemm128d (double-buf, 2 blocks/CU) best for GEMM2 (r12)

#define SWZ(x) ((x) ^ ((((x) >> 7) & 7) << 4))

#define BAR __builtin_amdgcn_s_barrier()
#define VMC(n) asm volatile("s_waitcnt vmcnt(" #n ")" ::: "memory")
#define PRIO1 __builtin_amdgcn_s_setprio(1)
#define PRIO0 __builtin_amdgcn_s_setprio(0)

#define LDA1(base, i, ks) \
  af[i][ks] = *(const bf16x8*)((base) + SWZ((wm * 64 + (i) * 16 + llo) * 128 + (ks) * 64 + lhi * 16))
#define LDB1(base, j, ks) \
  bf[j][ks] = *(const bf16x8*)((base) + SWZ((wn * 64 + (j) * 16 + llo) * 128 + (ks) * 64 + lhi * 16))
#define RDALL(Ab, Bb) do { \
  LDA1(Ab, 0, 0); LDA1(Ab, 1, 0); LDA1(Ab, 2, 0); LDA1(Ab, 3, 0); \
  LDB1(Bb, 0, 0); LDB1(Bb, 1, 0); LDB1(Bb, 2, 0); LDB1(Bb, 3, 0); \
  LDA1(Ab, 0, 1); LDA1(Ab, 1, 1); LDA1(Ab, 2, 1); LDA1(Ab, 3, 1); \
  LDB1(Bb, 0, 1); LDB1(Bb, 1, 1); LDB1(Bb, 2, 1); LDB1(Bb, 3, 1); } while (0)

#define MF1(m, n, ks) \
  acc[m][n] = __builtin_amdgcn_mfma_f32_16x16x32_bf16(af[m][ks], bf[n][ks], acc[m][n], 0, 0, 0)
#define MFALL do { PRIO1; \
  MF1(0,0,0); MF1(0,1,0); MF1(0,2,0); MF1(0,3,0); \
  MF1(1,0,0); MF1(1,1,0); MF1(1,2,0); MF1(1,3,0); \
  MF1(2,0,0); MF1(2,1,0); MF1(2,2,0); MF1(2,3,0); \
  MF1(3,0,0); MF1(3,1,0); MF1(3,2,0); MF1(3,3,0); \
  MF1(0,0,1); MF1(0,1,1); MF1(0,2,1); MF1(0,3,1); \
  MF1(1,0,1); MF1(1,1,1); MF1(1,2,1); MF1(1,3,1); \
  MF1(2,0,1); MF1(2,1,1); MF1(2,2,1); MF1(2,3,1); \
  MF1(3,0,1); MF1(3,1,1); MF1(3,2,1); MF1(3,3,1); \
  PRIO0; } while (0)

#define CWRITE do { \
  _Pragma("unroll") \
  for (int m = 0; m < 4; ++m) { \
    _Pragma("unroll") \
    for (int n = 0; n < 4; ++n) { \
      int row = brow + wm * 64 + m * 16 + lhi * 4; \
      int col = bcol + wn * 64 + n * 16 + llo; \
      _Pragma("unroll") \
      for (int r2 = 0; r2 < 4; ++r2) { \
        if (OUT_BF16) \
          ((bf16*)Cv)[(size_t)(row + r2) * Nn + col] = (bf16)acc[m][n][r2]; \
        else \
          ((float*)Cv)[(size_t)(row + r2) * Nn + col] = acc[m][n][r2]; \
      } \
    } \
  } } while (0)

#define GEMM_PREAMBLE \
  const int tid = threadIdx.x; \
  const int wave = tid >> 6, lane = tid & 63; \
  const int llo = lane & 15, lhi = lane >> 4; \
  const int wm = wave >> 1, wn = wave & 1; \
  const int nwg = gridDim.x, bid = blockIdx.x; \
  const int wg = (bid & 7) * (nwg >> 3) + (bid >> 3); \
  const int rb = wg / NBN, cb = wg - rb * NBN; \
  const int brow = rb * 128, bcol = cb * 128; \
  uint32_t srcA[4], srcB[4]; \
  _Pragma("unroll") \
  for (int q = 0; q < 4; ++q) { \
    int d = q * 4096 + tid * 16; \
    int a = SWZ(d); \
    int r = a >> 7, c = (a & 127) >> 1; \
    srcA[q] = (uint32_t)(brow + r) * GK + c; \
    srcB[q] = (uint32_t)(bcol + r) * GK + c; \
  } \
  f32x4 acc[4][4]; \
  _Pragma("unroll") \
  for (int m = 0; m < 4; ++m) \
    _Pragma("unroll") \
    for (int n = 0; n < 4; ++n) acc[m][n] = (f32x4){0.f, 0.f, 0.f, 0.f}; \
  bf16x8 af[4][2], bf[4][2];

// -------- variant S: single-buffer LDS (32 KiB), ~4-5 blocks/CU -----------
#define STAGE1(t) do { \
  gl_lds16(A  + srcA[0] + (t) * 64, &As_[0 * 2048 + wave * 512]); \
  gl_lds16(A  + srcA[1] + (t) * 64, &As_[1 * 2048 + wave * 512]); \
  gl_lds16(A  + srcA[2] + (t) * 64, &As_[2 * 2048 + wave * 512]); \
  gl_lds16(A  + srcA[3] + (t) * 64, &As_[3 * 2048 + wave * 512]); \
  gl_lds16(Bt + srcB[0] + (t) * 64, &Bs_[0 * 2048 + wave * 512]); \
  gl_lds16(Bt + srcB[1] + (t) * 64, &Bs_[1 * 2048 + wave * 512]); \
  gl_lds16(Bt + srcB[2] + (t) * 64, &Bs_[2 * 2048 + wave * 512]); \
  gl_lds16(Bt + srcB[3] + (t) * 64, &Bs_[3 * 2048 + wave * 512]); } while (0)

template <bool OUT_BF16>
__global__ __launch_bounds__(256, 2) void gemm128s(const bf16* __restrict__ A,
                                                   const bf16* __restrict__ Bt,
                                                   void* __restrict__ Cv,
                                                   int Nn, int NBN) {
  __shared__ __align__(16) bf16 As_[8192];
  __shared__ __align__(16) bf16 Bs_[8192];
  GEMM_PREAMBLE;

  STAGE1(0);
  VMC(0);
  BAR;

  #pragma unroll
  for (int t = 0; t < 12; ++t) {
    RDALL((const char*)As_, (const char*)Bs_);
    MFALL;
    if (t < 11) {
      BAR;
      STAGE1(t + 1);
      VMC(0);
      BAR;
    }
  }
  CWRITE;
}

// -------- variant D: double-buffer LDS (64 KiB), 2 blocks/CU --------------
#define STA2(b, q, t) gl_lds16(A + srcA[q] + (t) * 64, &As_[b][(q) * 2048 + wave * 512])
#define STB2(b, q, t) gl_lds16(Bt + srcB[q] + (t) * 64, &Bs_[b][(q) * 2048 + wave * 512])
#define STAGE2(b, t) do { \
  STA2(b, 0, t); STA2(b, 1, t); STA2(b, 2, t); STA2(b, 3, t); \
  STB2(b, 0, t); STB2(b, 1, t); STB2(b, 2, t); STB2(b, 3, t); } while (0)

template <bool OUT_BF16>
__global__ __launch_bounds__(256, 2) void gemm128d(const bf16* __restrict__ A,
                                                   const bf16* __restrict__ Bt,
                                                   void* __restrict__ Cv,
                                                   int Nn, int NBN) {
  __shared__ __align__(16) bf16 As_[2][8192];
  __shared__ __align__(16) bf16 Bs_[2][8192];
  GEMM_PREAMBLE;

  const char* As0 = (const char*)&As_[0][0];
  const char* As1 = (const char*)&As_[1][0];
  const char* Bs0 = (const char*)&Bs_[0][0];
  const char* Bs1 = (const char*)&Bs_[1][0];

  STAGE2(0, 0);
  STAGE2(1, 1);
  VMC(8);
  BAR;

  #pragma unroll
  for (int j = 0; j < 5; ++j) {
    RDALL(As0, Bs0);
    MFALL;
    BAR;
    STAGE2(0, 2 * j + 2);
    VMC(8);
    BAR;
    RDALL(As1, Bs1);
    MFALL;
    BAR;
    STAGE2(1, 2 * j + 3);
    VMC(8);
    BAR;
  }
  RDALL(As0, Bs0);
  MFALL;
  BAR;
  VMC(0);
  BAR;
  RDALL(As1, Bs1);
  MFALL;
  CWRITE;
}

// ---------------- 3a: kv partial sums, k-norm inline, 4 blocks/CU ----------
__global__ __launch_bounds__(256) void kv_partial(const bf16* __restrict__ qkv,
                                                  float* __restrict__ kvp) {
  __shared__ float sm[4][768];
  int b = blockIdx.x >> 7, chunk = blockIdx.x & 127;
  int wave = threadIdx.x >> 6, lane = threadIdx.x & 63;
  const bf16* base = qkv + ((size_t)(b * 4096 + chunk * 32 + wave * 8)) * 2304;
  float acc8[8] = {}, acc4[4] = {};
  #pragma unroll
  for (int i = 0; i < 8; ++i) {
    const bf16* kr = base + (size_t)i * 2304 + 768;
    const bf16* vr = kr + 768;
    bf16x8 k8 = *(const bf16x8*)(kr + lane * 8);
    bf16x4 k4 = *(const bf16x4*)(kr + 512 + lane * 4);
    bf16x8 v8 = *(const bf16x8*)(vr + lane * 8);
    bf16x4 v4 = *(const bf16x4*)(vr + 512 + lane * 4);
    float kf8[8], kf4[4];
    float ssk = 0.f;
    #pragma unroll
    for (int j = 0; j < 8; ++j) { kf8[j] = (float)k8[j]; ssk += kf8[j] * kf8[j]; }
    #pragma unroll
    for (int j = 0; j < 4; ++j) { kf4[j] = (float)k4[j]; ssk += kf4[j] * kf4[j]; }
    #pragma unroll
    for (int off = 32; off > 0; off >>= 1) ssk += __shfl_xor(ssk, off, 64);
    float wi = 1.0f / fmaxf(sqrtf(ssk), NORM_EPS);
    #pragma unroll
    for (int j = 0; j < 8; ++j) acc8[j] += kf8[j] * (float)v8[j] * wi;
    #pragma unroll
    for (int j = 0; j < 4; ++j) acc4[j] += kf4[j] * (float)v4[j] * wi;
  }
  #pragma unroll
  for (int j = 0; j < 8; ++j) sm[wave][lane * 8 + j] = acc8[j];
  #pragma unroll
  for (int j = 0; j < 4; ++j) sm[wave][512 + lane * 4 + j] = acc4[j];
  __syncthreads();
  int t = threadIdx.x;
  #pragma unroll
  for (int c = 0; c < 3; ++c) {
    int e = c * 256 + t;
    kvp[(size_t)blockIdx.x * 768 + e] = sm[0][e] + sm[1][e] + sm[2][e] + sm[3][e];
  }
}

// ---------------- 3b: reduce 128 partials -> kv[8][768] ----------------
__global__ __launch_bounds__(256) void kv_reduce(const float* __restrict__ kvp,
                                                 float* __restrict__ kv) {
  int i = blockIdx.x * 256 + threadIdx.x;
  int b = i / 768, e = i - b * 768;
  float s = 0.f;
  #pragma unroll 8
  for (int c = 0; c < 128; ++c) s += kvp[(size_t)(b * 128 + c) * 768 + e];
  kv[i] = s;
}

// ---------------- 4: attn+LN, wave-per-row (q-norm inline) ----------------
__global__ __launch_bounds__(256) void attn_ln_kernel(const bf16* __restrict__ qkv,
                                                      const float* __restrict__ kv,
                                                      const float* __restrict__ g,
                                                      const float* __restrict__ b,
                                                      bf16* __restrict__ a) {
  int wave = threadIdx.x >> 6, lane = threadIdx.x & 63;
  int row = blockIdx.x * 4 + wave;
  int bt = row >> 12;
  const bf16* qr = qkv + (size_t)row * 2304;
  bf16x4 q4[3];
  float qf[12];
  float sq = 0.f;
  #pragma unroll
  for (int c = 0; c < 3; ++c) {
    q4[c] = ((const bf16x4*)qr)[lane + c * 64];
    #pragma unroll
    for (int j = 0; j < 4; ++j) {
      float f = (float)q4[c][j];
      qf[c * 4 + j] = f;
      sq += f * f;
    }
  }
  #pragma unroll
  for (int o = 32; o > 0; o >>= 1) sq += __shfl_xor(sq, o, 64);
  float iq = 1.0f / fmaxf(sqrtf(sq), NORM_EPS);
  const float4* kvr = (const float4*)(kv + bt * 768);
  float av[12];
  float s = 0.f, ss = 0.f;
  #pragma unroll
  for (int c = 0; c < 3; ++c) {
    float4 kv4 = kvr[lane + c * 64];
    av[c * 4 + 0] = qf[c * 4 + 0] * iq * kv4.x;
    av[c * 4 + 1] = qf[c * 4 + 1] * iq * kv4.y;
    av[c * 4 + 2] = qf[c * 4 + 2] * iq * kv4.z;
    av[c * 4 + 3] = qf[c * 4 + 3] * iq * kv4.w;
    #pragma unroll
    for (int j = 0; j < 4; ++j) { s += av[c * 4 + j]; ss += av[c * 4 + j] * av[c * 4 + j]; }
  }
  #pragma unroll
  for (int o = 32; o > 0; o >>= 1) {
    s  += __shfl_xor(s, o, 64);
    ss += __shfl_xor(ss, o, 64);
  }
  float mu  = s * (1.0f / 768.0f);
  float inv = rsqrtf(ss * (1.0f / 768.0f) - mu * mu + LN_EPS);
  bf16* ar = a + (size_t)row * 768;
  #pragma unroll
  for (int c = 0; c < 3; ++c) {
    float4 gg = ((const float4*)g)[lane + c * 64];
    float4 bb = ((const float4*)b)[lane + c * 64];
    bf16x4 o;
    o[0] = (bf16)((av[c * 4 + 0] - mu) * inv * gg.x + bb.x);
    o[1] = (bf16)((av[c * 4 + 1] - mu) * inv * gg.y + bb.y);
    o[2] = (bf16)((av[c * 4 + 2] - mu) * inv * gg.z + bb.z);
    o[3] = (bf16)((av[c * 4 + 3] - mu) * inv * gg.w + bb.w);
    ((bf16x4*)ar)[lane + c * 64] = o;
  }
}

// ---------------- launcher ----------------
extern "C" void kernel_launch(void* const* d_in, const int* in_sizes, int n_in,
                              void* d_out, int out_size, void* d_ws, size_t ws_size,
                              hipStream_t stream) {
  const float* x      = (const float*)d_in[0];
  const float* w_qkv  = (const float*)d_in[1];
  const float* w_proj = (const float*)d_in[2];
  const float* g_in   = (const float*)d_in[3];
  const float* b_in   = (const float*)d_in[4];
  const float* g_out  = (const float*)d_in[5];
  const float* b_out  = (const float*)d_in[6];

  char* ws = (char*)d_ws;
  bf16*  wqkvt  = (bf16*)(ws);                              // [2304][768] bf16
  bf16*  wprojt = (bf16*)(ws + 3538944);                    // [768][768]  bf16
  bf16*  h      = (bf16*)(ws + 4718592);                    // [32768][768] bf16 (reused as 'a')
  bf16*  qkv    = (bf16*)(ws + 55050240);                   // [32768][2304] bf16
  float* kvp    = (float*)(ws + 206045184);                 // [1024][768] fp32
  float* kv     = (float*)(ws + 209190912);                 // [8][768]

  transpose_cvt2<<<2304, 256, 0, stream>>>(w_qkv, w_proj, wqkvt, wprojt);
  ln_in_kernel<<<8192, 256, 0, stream>>>(x, g_in, b_in, h);
  gemm128s<true><<<256 * 18, 256, 0, stream>>>(h, wqkvt, (void*)qkv, 2304, 18);
  kv_partial<<<1024, 256, 0, stream>>>(qkv, kvp);
  kv_reduce<<<24, 256, 0, stream>>>(kvp, kv);
  attn_ln_kernel<<<8192, 256, 0, stream>>>(qkv, kv, g_out, b_out, h);
  gemm128d<false><<<256 * 6, 256, 0, stream>>>(h, wprojt, d_out, 768, 6);
}